// Round 1
// baseline (8073.811 us; speedup 1.0000x reference)
//
#include <hip/hip_runtime.h>
#include <hip/hip_bf16.h>
#include <math.h>

// Problem constants
#define Bsz 256
#define Hh 26
#define Ww 26
#define Ll 624
#define DDc 128
#define CHc 256
#define NLl 4
#define NPIX (Hh * Ww)            // 676
#define NROWS (Bsz * NPIX)        // 173056
#define GRID_ELEMS (NROWS * DDc)  // 22151168 floats per grid buffer

#define LDSW 34                   // padded LDS width (cols 0..33), avoids OOB for px-group 3

// ---------------------------------------------------------------------------
// Build inverse map pos -> l (or -1)
__global__ void build_inv_kernel(const int* __restrict__ coords, int* __restrict__ inv) {
    int i = threadIdx.x;
    if (i < NPIX) inv[i] = -1;
    __syncthreads();
    if (i < Ll) {
        int r = coords[2 * i + 0];
        int c = coords[2 * i + 1];
        inv[r * Ww + c] = i;
    }
}

// ---------------------------------------------------------------------------
// Scatter: Y[b,pos,:] = X[b,inv[pos],:] if inv>=0 else P[:]
__global__ __launch_bounds__(256) void scatter_kernel(const float* __restrict__ X,
                                                      const float* __restrict__ P,
                                                      const int* __restrict__ inv,
                                                      float* __restrict__ Y) {
    int idx = blockIdx.x * blockDim.x + threadIdx.x;     // one float4 per thread
    int r = idx >> 5;            // row = b*676 + pos
    int c4 = idx & 31;
    int b = r / NPIX;
    int pos = r - b * NPIX;
    int li = inv[pos];
    float4 v;
    if (li >= 0) {
        v = *(const float4*)(X + ((size_t)(b * Ll + li) * DDc + c4 * 4));
    } else {
        v = *(const float4*)(P + c4 * 4);
    }
    *(float4*)(Y + ((size_t)r * DDc + c4 * 4)) = v;
}

// ---------------------------------------------------------------------------
// LayerNorm over channel dim (128) : one wave (64 lanes) per row, float2/lane
__global__ __launch_bounds__(256) void ln_kernel(const float* __restrict__ Y,
                                                 const float* __restrict__ scale,
                                                 const float* __restrict__ bias,
                                                 float* __restrict__ Yn) {
    int wave = threadIdx.x >> 6;
    int lane = threadIdx.x & 63;
    int r = blockIdx.x * 4 + wave;
    const float* yr = Y + (size_t)r * DDc;
    float2 v = *(const float2*)(yr + lane * 2);
    float s = v.x + v.y;
#pragma unroll
    for (int off = 32; off >= 1; off >>= 1) s += __shfl_xor(s, off, 64);
    float mean = s * (1.0f / 128.0f);
    float dx = v.x - mean, dy = v.y - mean;
    float s2 = dx * dx + dy * dy;
#pragma unroll
    for (int off = 32; off >= 1; off >>= 1) s2 += __shfl_xor(s2, off, 64);
    float rstd = rsqrtf(s2 * (1.0f / 128.0f) + 1e-5f);
    float2 sc = *(const float2*)(scale + lane * 2);
    float2 bi = *(const float2*)(bias + lane * 2);
    float2 o;
    o.x = dx * rstd * sc.x + bi.x;
    o.y = dy * rstd * sc.y + bi.y;
    *(float2*)(Yn + (size_t)r * DDc + lane * 2) = o;
}

// ---------------------------------------------------------------------------
// Fused: conv3x3(DD->CH) + b3 + gelu(exact) + 1x1(CH->DD) + b1 + residual add
// One block per (b, h) row of the grid. 256 threads.
//   conv phase: thread = (pxGroup = tid>>6, chGroup = tid&63)
//               acc[8 px][4 ch], inner loop over (tap, cin4)
//   1x1 phase : thread = (half = tid>>7, d = tid&127), 13 px each
__global__ __launch_bounds__(256, 2) void conv_fused_kernel(const float* __restrict__ Yn,
                                                            const float* __restrict__ w3l,
                                                            const float* __restrict__ b3l,
                                                            const float* __restrict__ w1l,
                                                            const float* __restrict__ b1l,
                                                            float* __restrict__ Y) {
    __shared__ float lds[3 * LDSW * DDc];   // 13056 floats = 52224 B; reused for hidden[26][256]

    int b = blockIdx.x / Hh;
    int h = blockIdx.x - b * Hh;
    int tid = threadIdx.x;

    // ---- stage 3 input rows (zero-padded) into LDS: layout [row3][LDSW][128]
    const int nF4 = 3 * LDSW * (DDc / 4);   // 3264 float4
    for (int i = tid; i < nF4; i += 256) {
        int row3 = i / (LDSW * 32);
        int rem = i - row3 * (LDSW * 32);
        int wi = rem / 32;
        int c4 = rem - wi * 32;
        int hs = h - 1 + row3;
        int ws = wi - 1;
        float4 v = make_float4(0.f, 0.f, 0.f, 0.f);
        if (hs >= 0 && hs < Hh && ws >= 0 && ws < Ww) {
            v = *(const float4*)(Yn + (((size_t)(b * Hh + hs) * Ww + ws) * DDc + c4 * 4));
        }
        *(float4*)(lds + (size_t)i * 4) = v;
    }
    __syncthreads();

    // ---- conv 3x3
    int chGroup = tid & 63;
    int ch0 = chGroup * 4;
    int pxg = tid >> 6;
    int wbase = pxg * 8;   // pixels wbase..wbase+7 (group 3: only 24,25 valid; rest discarded)

    float acc[8][4];
#pragma unroll
    for (int p = 0; p < 8; ++p)
#pragma unroll
        for (int j = 0; j < 4; ++j) acc[p][j] = 0.f;

    for (int tap = 0; tap < 9; ++tap) {
        int dh = tap / 3;
        int dw = tap - dh * 3;
        const float* wt = w3l + (size_t)(tap * DDc) * CHc + ch0;
        int ldsbase = (dh * LDSW + wbase + dw) * DDc;
        for (int cin4 = 0; cin4 < 32; ++cin4) {
            int cin = cin4 * 4;
            float4 wv0 = *(const float4*)(wt + (size_t)(cin + 0) * CHc);
            float4 wv1 = *(const float4*)(wt + (size_t)(cin + 1) * CHc);
            float4 wv2 = *(const float4*)(wt + (size_t)(cin + 2) * CHc);
            float4 wv3 = *(const float4*)(wt + (size_t)(cin + 3) * CHc);
#pragma unroll
            for (int p = 0; p < 8; ++p) {
                float4 a = *(const float4*)(lds + ldsbase + p * DDc + cin);
                acc[p][0] += a.x * wv0.x + a.y * wv1.x + a.z * wv2.x + a.w * wv3.x;
                acc[p][1] += a.x * wv0.y + a.y * wv1.y + a.z * wv2.y + a.w * wv3.y;
                acc[p][2] += a.x * wv0.z + a.y * wv1.z + a.z * wv2.z + a.w * wv3.z;
                acc[p][3] += a.x * wv0.w + a.y * wv1.w + a.z * wv2.w + a.w * wv3.w;
            }
        }
    }
    __syncthreads();   // done reading ldsIn

    // ---- bias + exact gelu, store hidden[26][256] into LDS
    float4 bv = *(const float4*)(b3l + ch0);
#pragma unroll
    for (int p = 0; p < 8; ++p) {
        int w = wbase + p;
        if (w < Ww) {
            float4 g;
            float x0 = acc[p][0] + bv.x;
            float x1 = acc[p][1] + bv.y;
            float x2 = acc[p][2] + bv.z;
            float x3 = acc[p][3] + bv.w;
            g.x = 0.5f * x0 * (1.0f + erff(x0 * 0.70710678118654752f));
            g.y = 0.5f * x1 * (1.0f + erff(x1 * 0.70710678118654752f));
            g.z = 0.5f * x2 * (1.0f + erff(x2 * 0.70710678118654752f));
            g.w = 0.5f * x3 * (1.0f + erff(x3 * 0.70710678118654752f));
            *(float4*)(lds + w * CHc + ch0) = g;
        }
    }
    __syncthreads();

    // ---- 1x1: out[px][d] = sum_ch hidden[px][ch] * w1[ch][d]; += b1; residual into Y
    int d = tid & 127;
    int half = tid >> 7;
    float out[13];
#pragma unroll
    for (int k = 0; k < 13; ++k) out[k] = 0.f;

    for (int ch4 = 0; ch4 < 64; ++ch4) {
        int ch = ch4 * 4;
        float w0 = w1l[(size_t)(ch + 0) * DDc + d];
        float w1v = w1l[(size_t)(ch + 1) * DDc + d];
        float w2 = w1l[(size_t)(ch + 2) * DDc + d];
        float w3v = w1l[(size_t)(ch + 3) * DDc + d];
#pragma unroll
        for (int k = 0; k < 13; ++k) {
            int px = half * 13 + k;
            float4 hv = *(const float4*)(lds + px * CHc + ch);
            out[k] += hv.x * w0 + hv.y * w1v + hv.z * w2 + hv.w * w3v;
        }
    }

    float bb = b1l[d];
#pragma unroll
    for (int k = 0; k < 13; ++k) {
        int px = half * 13 + k;
        float* yp = Y + (((size_t)(b * Hh + h) * Ww + px) * DDc + d);
        *yp += out[k] + bb;
    }
}

// ---------------------------------------------------------------------------
// Gather: Z[b,l,:] = Y[b, rows[l], cols[l], :]
__global__ __launch_bounds__(256) void gather_kernel(const float* __restrict__ Y,
                                                     const int* __restrict__ coords,
                                                     float* __restrict__ Z) {
    int idx = blockIdx.x * blockDim.x + threadIdx.x;   // one float4 per thread
    int r = idx >> 5;          // r = b*624 + l
    int c4 = idx & 31;
    int b = r / Ll;
    int li = r - b * Ll;
    int row = coords[2 * li + 0];
    int col = coords[2 * li + 1];
    float4 v = *(const float4*)(Y + (((size_t)(b * NPIX + row * Ww + col)) * DDc + c4 * 4));
    *(float4*)(Z + ((size_t)r * DDc + c4 * 4)) = v;
}

// ---------------------------------------------------------------------------
extern "C" void kernel_launch(void* const* d_in, const int* in_sizes, int n_in,
                              void* d_out, int out_size, void* d_ws, size_t ws_size,
                              hipStream_t stream) {
    const float* X = (const float*)d_in[0];
    const int* coords = (const int*)d_in[1];
    const float* P = (const float*)d_in[2];
    const float* ln_scale = (const float*)d_in[3];
    const float* ln_bias = (const float*)d_in[4];
    const float* w3 = (const float*)d_in[5];
    const float* b3 = (const float*)d_in[6];
    const float* w1 = (const float*)d_in[7];
    const float* b1 = (const float*)d_in[8];

    float* Y = (float*)d_ws;
    float* Yn = Y + GRID_ELEMS;
    int* inv = (int*)(Yn + GRID_ELEMS);

    build_inv_kernel<<<1, 1024, 0, stream>>>(coords, inv);

    // scatter: B*676*32 float4-threads
    {
        int total = NROWS * 32;
        scatter_kernel<<<total / 256, 256, 0, stream>>>(X, P, inv, Y);
    }

    for (int l = 0; l < NLl; ++l) {
        ln_kernel<<<NROWS / 4, 256, 0, stream>>>(Y, ln_scale + l * DDc, ln_bias + l * DDc, Yn);
        conv_fused_kernel<<<Bsz * Hh, 256, 0, stream>>>(
            Yn,
            w3 + (size_t)l * 9 * DDc * CHc,
            b3 + (size_t)l * CHc,
            w1 + (size_t)l * CHc * DDc,
            b1 + (size_t)l * DDc,
            Y);
    }

    // gather: B*624*32 float4-threads
    {
        int total = Bsz * Ll * 32;
        gather_kernel<<<total / 256, 256, 0, stream>>>(Y, coords, (float*)d_out);
    }
}

// Round 2
// 1674.563 us; speedup vs baseline: 4.8214x; 4.8214x over previous
//
#include <hip/hip_runtime.h>
#include <hip/hip_bf16.h>
#include <math.h>

// Problem constants
#define Bsz 256
#define Hh 26
#define Ww 26
#define Ll 624
#define DDc 128
#define CHc 256
#define NLl 4
#define NPIX (Hh * Ww)            // 676
#define NROWS (Bsz * NPIX)        // 173056
#define GRID_ELEMS (NROWS * DDc)  // 22151168

typedef short short8v __attribute__((ext_vector_type(8)));   // 8 bf16 (4 VGPRs)
typedef float f32x4 __attribute__((ext_vector_type(4)));

__device__ __forceinline__ unsigned short f2bf(float f) {
    union { float f; unsigned int u; } v; v.f = f;
    unsigned int u = v.u;
    return (unsigned short)((u + 0x7FFFu + ((u >> 16) & 1u)) >> 16);   // RNE
}

// ---------------------------------------------------------------------------
__global__ void build_inv_kernel(const int* __restrict__ coords, int* __restrict__ inv) {
    int i = threadIdx.x;
    if (i < NPIX) inv[i] = -1;
    __syncthreads();
    if (i < Ll) {
        int r = coords[2 * i + 0];
        int c = coords[2 * i + 1];
        inv[r * Ww + c] = i;
    }
}

// ---------------------------------------------------------------------------
// Scatter: Y[b,pos,:] = X[b,inv[pos],:] if inv>=0 else P[:]   (fp32 grid)
__global__ __launch_bounds__(256) void scatter_kernel(const float* __restrict__ X,
                                                      const float* __restrict__ P,
                                                      const int* __restrict__ inv,
                                                      float* __restrict__ Y) {
    int idx = blockIdx.x * blockDim.x + threadIdx.x;
    int r = idx >> 5;
    int c4 = idx & 31;
    int b = r / NPIX;
    int pos = r - b * NPIX;
    int li = inv[pos];
    float4 v;
    if (li >= 0) v = *(const float4*)(X + ((size_t)(b * Ll + li) * DDc + c4 * 4));
    else         v = *(const float4*)(P + c4 * 4);
    *(float4*)(Y + ((size_t)r * DDc + c4 * 4)) = v;
}

// ---------------------------------------------------------------------------
// Weight transpose + bf16 convert: in [R][C] f32 (batch z) -> out [C][R] bf16
__global__ __launch_bounds__(256) void wprep_kernel(const float* __restrict__ in,
                                                    unsigned short* __restrict__ out,
                                                    int R, int C) {
    __shared__ float t[32][33];
    int bz = blockIdx.z;
    const float* ip = in + (size_t)bz * R * C;
    unsigned short* op = out + (size_t)bz * R * C;
    int c0 = blockIdx.x * 32, r0 = blockIdx.y * 32;
    int tx = threadIdx.x & 31, ty = threadIdx.x >> 5;   // 32 x 8
#pragma unroll
    for (int i = 0; i < 32; i += 8)
        t[ty + i][tx] = ip[(size_t)(r0 + ty + i) * C + c0 + tx];
    __syncthreads();
#pragma unroll
    for (int i = 0; i < 32; i += 8)
        op[(size_t)(c0 + ty + i) * R + r0 + tx] = f2bf(t[tx][ty + i]);
}

// ---------------------------------------------------------------------------
// LayerNorm: fp32 in -> bf16 out. One wave per row, 2 ch/lane.
__global__ __launch_bounds__(256) void ln_kernel(const float* __restrict__ Y,
                                                 const float* __restrict__ scale,
                                                 const float* __restrict__ bias,
                                                 unsigned short* __restrict__ Yn) {
    int wave = threadIdx.x >> 6;
    int lane = threadIdx.x & 63;
    int r = blockIdx.x * 4 + wave;
    const float* yr = Y + (size_t)r * DDc;
    float2 v = *(const float2*)(yr + lane * 2);
    float s = v.x + v.y;
#pragma unroll
    for (int off = 32; off >= 1; off >>= 1) s += __shfl_xor(s, off, 64);
    float mean = s * (1.0f / 128.0f);
    float dx = v.x - mean, dy = v.y - mean;
    float s2 = dx * dx + dy * dy;
#pragma unroll
    for (int off = 32; off >= 1; off >>= 1) s2 += __shfl_xor(s2, off, 64);
    float rstd = rsqrtf(s2 * (1.0f / 128.0f) + 1e-5f);
    float2 sc = *(const float2*)(scale + lane * 2);
    float2 bi = *(const float2*)(bias + lane * 2);
    ushort2 o;
    o.x = f2bf(dx * rstd * sc.x + bi.x);
    o.y = f2bf(dy * rstd * sc.y + bi.y);
    *(ushort2*)(Yn + (size_t)r * DDc + lane * 2) = o;
}

// ---------------------------------------------------------------------------
// Fused MFMA layer kernel: conv3x3(128->256) + b3 + gelu + 1x1(256->128) + b1 + residual
// Block = (b, row-pair). 256 threads = 4 waves. M = 52 px padded to 64 (4 m-tiles).
// Wave w owns conv cols [w*64, w*64+64) (4 n-tiles), 1x1 cols [w*32, w*32+32) (2 n-tiles).
#define A_BYTES (4 * 28 * 128 * 2)        // 28672
#define H_OFF   A_BYTES
#define H_BYTES (64 * 256 * 2)            // 32768
#define Z_OFF   (H_OFF + H_BYTES)
#define LDS_TOTAL (Z_OFF + 256)           // 61696 B -> 2 blocks/CU

__global__ __launch_bounds__(256) void conv_mfma_kernel(
    const unsigned short* __restrict__ Yn,
    const unsigned short* __restrict__ w3bt,   // [9][256 n][128 k] bf16
    const float* __restrict__ b3l,
    const unsigned short* __restrict__ w1bt,   // [128 n][256 k] bf16
    const float* __restrict__ b1l,
    float* __restrict__ Y) {
    __shared__ __align__(16) char lds[LDS_TOTAL];

    int bx = blockIdx.x;
    int b = bx / 13;
    int h0 = (bx - b * 13) * 2;
    int tid = threadIdx.x;
    int lane = tid & 63, wv = tid >> 6;
    int al = lane & 15, ah = lane >> 4;

    // ---- stage A: rows h0-1..h0+2, cols -1..26, 128ch bf16, XOR-swizzled
    for (int i = tid; i < 4 * 28 * 16; i += 256) {     // 16B chunks
        int row4 = i / (28 * 16);
        int rem = i - row4 * (28 * 16);
        int col = rem >> 4;
        int c8 = (rem & 15) << 3;                      // channel base
        int hs = h0 - 1 + row4;
        int ws = col - 1;
        uint4 v = make_uint4(0u, 0u, 0u, 0u);
        if (hs >= 0 && hs < Hh && ws >= 0 && ws < Ww)
            v = *(const uint4*)(Yn + (((size_t)(b * Hh + hs) * Ww + ws) << 7) + c8);
        int r = row4 * 28 + col;
        unsigned int addr = (unsigned int)(r * 256 + c8 * 2);
        addr ^= (unsigned int)((r & 7) << 4);
        *(uint4*)(lds + addr) = v;
    }
    if (tid < 16) *(uint4*)(lds + Z_OFF + tid * 16) = make_uint4(0u, 0u, 0u, 0u);
    __syncthreads();

    // ---- per-lane M decomposition
    int r00[4]; bool mpad[4];
#pragma unroll
    for (int mt = 0; mt < 4; ++mt) {
        int m = mt * 16 + al;
        bool pad = (m >= 52);
        int rh = (m >= 26) ? 1 : 0;
        int w = m - rh * 26;
        if (pad) { rh = 1; w = 0; }
        mpad[mt] = pad;
        r00[mt] = rh * 28 + w;
    }

    // ---- conv 3x3 via MFMA, K = 9 taps x 128
    f32x4 acc[4][4];
#pragma unroll
    for (int mt = 0; mt < 4; ++mt)
#pragma unroll
        for (int nt = 0; nt < 4; ++nt) acc[mt][nt] = (f32x4)0.0f;

    int nw0 = wv * 64;
    const unsigned short* pB = w3bt + ((size_t)(nw0 + al) << 7) + ah * 8;

#pragma unroll 1
    for (int tap = 0; tap < 9; ++tap) {
        int dh = tap / 3;
        int dw = tap - dh * 3;
        int roff = dh * 28 + dw;
        const unsigned short* pBt = pB + (size_t)tap * (CHc * DDc);
#pragma unroll
        for (int ks = 0; ks < 4; ++ks) {
            short8v af[4], bfr[4];
#pragma unroll
            for (int mt = 0; mt < 4; ++mt) {
                int r = r00[mt] + roff;
                unsigned int addr = (unsigned int)(r * 256 + ks * 64 + ah * 16)
                                    ^ (unsigned int)((r & 7) << 4);
                if (mpad[mt]) addr = Z_OFF + ah * 16;
                af[mt] = *(const short8v*)(lds + addr);
            }
#pragma unroll
            for (int nt = 0; nt < 4; ++nt)
                bfr[nt] = *(const short8v*)(pBt + nt * (16 * DDc) + ks * 32);
#pragma unroll
            for (int mt = 0; mt < 4; ++mt)
#pragma unroll
                for (int nt = 0; nt < 4; ++nt)
                    acc[mt][nt] = __builtin_amdgcn_mfma_f32_16x16x32_bf16(
                        af[mt], bfr[nt], acc[mt][nt], 0, 0, 0);
        }
    }

    // ---- bias + exact gelu -> H lds [64 m][256 n] bf16 (XOR-swizzled rows)
#pragma unroll
    for (int nt = 0; nt < 4; ++nt) {
        int n = nw0 + nt * 16 + al;
        float bias = b3l[n];
#pragma unroll
        for (int mt = 0; mt < 4; ++mt) {
#pragma unroll
            for (int j = 0; j < 4; ++j) {
                int m = mt * 16 + ah * 4 + j;
                float x = acc[mt][nt][j] + bias;
                float g = 0.5f * x * (1.0f + erff(x * 0.70710678118654752f));
                unsigned int addr = (unsigned int)(m * 512 + n * 2)
                                    ^ (unsigned int)((m & 7) << 4);
                *(unsigned short*)(lds + H_OFF + addr) = f2bf(g);
            }
        }
    }
    __syncthreads();

    // ---- 1x1 via MFMA: [64 x 256] @ [256 x 128]
    f32x4 acc1[4][2];
#pragma unroll
    for (int mt = 0; mt < 4; ++mt) { acc1[mt][0] = (f32x4)0.0f; acc1[mt][1] = (f32x4)0.0f; }
    int nw1 = wv * 32;
    const unsigned short* pW1 = w1bt + ((size_t)(nw1 + al) << 8) + ah * 8;
    unsigned int hx = ((unsigned int)(al & 7)) << 4;   // (m&7)==(al&7)

#pragma unroll
    for (int ks = 0; ks < 8; ++ks) {
        short8v hf[4], wf[2];
#pragma unroll
        for (int mt = 0; mt < 4; ++mt) {
            int m = mt * 16 + al;
            unsigned int addr = ((unsigned int)(m * 512 + ks * 64 + ah * 16)) ^ hx;
            hf[mt] = *(const short8v*)(lds + H_OFF + addr);
        }
        wf[0] = *(const short8v*)(pW1 + ks * 32);
        wf[1] = *(const short8v*)(pW1 + 16 * 256 + ks * 32);
#pragma unroll
        for (int mt = 0; mt < 4; ++mt)
#pragma unroll
            for (int ntl = 0; ntl < 2; ++ntl)
                acc1[mt][ntl] = __builtin_amdgcn_mfma_f32_16x16x32_bf16(
                    hf[mt], wf[ntl], acc1[mt][ntl], 0, 0, 0);
    }

    // ---- bias + residual into Y (fp32)
#pragma unroll
    for (int ntl = 0; ntl < 2; ++ntl) {
        int n = nw1 + ntl * 16 + al;
        float bias = b1l[n];
#pragma unroll
        for (int mt = 0; mt < 4; ++mt) {
#pragma unroll
            for (int j = 0; j < 4; ++j) {
                int m = mt * 16 + ah * 4 + j;
                if (m < 52) {
                    int rh = (m >= 26) ? 1 : 0;
                    int w = m - rh * 26;
                    float* yp = Y + (((size_t)(b * Hh + h0 + rh) * Ww + w) << 7) + n;
                    *yp += acc1[mt][ntl][j] + bias;
                }
            }
        }
    }
}

// ---------------------------------------------------------------------------
__global__ __launch_bounds__(256) void gather_kernel(const float* __restrict__ Y,
                                                     const int* __restrict__ coords,
                                                     float* __restrict__ Z) {
    int idx = blockIdx.x * blockDim.x + threadIdx.x;
    int r = idx >> 5;
    int c4 = idx & 31;
    int b = r / Ll;
    int li = r - b * Ll;
    int row = coords[2 * li + 0];
    int col = coords[2 * li + 1];
    float4 v = *(const float4*)(Y + (((size_t)(b * NPIX + row * Ww + col)) * DDc + c4 * 4));
    *(float4*)(Z + ((size_t)r * DDc + c4 * 4)) = v;
}

// ---------------------------------------------------------------------------
extern "C" void kernel_launch(void* const* d_in, const int* in_sizes, int n_in,
                              void* d_out, int out_size, void* d_ws, size_t ws_size,
                              hipStream_t stream) {
    const float* X = (const float*)d_in[0];
    const int* coords = (const int*)d_in[1];
    const float* P = (const float*)d_in[2];
    const float* ln_scale = (const float*)d_in[3];
    const float* ln_bias = (const float*)d_in[4];
    const float* w3 = (const float*)d_in[5];
    const float* b3 = (const float*)d_in[6];
    const float* w1 = (const float*)d_in[7];
    const float* b1 = (const float*)d_in[8];

    float* Y = (float*)d_ws;
    unsigned short* Yn = (unsigned short*)(Y + GRID_ELEMS);
    unsigned short* w3bt = Yn + GRID_ELEMS;
    unsigned short* w1bt = w3bt + (size_t)NLl * 9 * CHc * DDc;
    int* inv = (int*)(w1bt + (size_t)NLl * DDc * CHc);

    build_inv_kernel<<<1, 1024, 0, stream>>>(coords, inv);

    // weight prep: w3 [l*9 slabs of 128x256] -> [256][128] bf16 ; w1 [256x128] -> [128][256]
    wprep_kernel<<<dim3(CHc / 32, DDc / 32, NLl * 9), 256, 0, stream>>>(w3, w3bt, DDc, CHc);
    wprep_kernel<<<dim3(DDc / 32, CHc / 32, NLl), 256, 0, stream>>>(w1, w1bt, CHc, DDc);

    scatter_kernel<<<(NROWS * 32) / 256, 256, 0, stream>>>(X, P, inv, Y);

    for (int l = 0; l < NLl; ++l) {
        ln_kernel<<<NROWS / 4, 256, 0, stream>>>(Y, ln_scale + l * DDc, ln_bias + l * DDc, Yn);
        conv_mfma_kernel<<<Bsz * 13, 256, 0, stream>>>(
            Yn,
            w3bt + (size_t)l * 9 * CHc * DDc,
            b3 + (size_t)l * CHc,
            w1bt + (size_t)l * DDc * CHc,
            b1 + (size_t)l * DDc,
            Y);
    }

    gather_kernel<<<(Bsz * Ll * 32) / 256, 256, 0, stream>>>(Y, coords, (float*)d_out);
}

// Round 4
// 1322.987 us; speedup vs baseline: 6.1027x; 1.2657x over previous
//
#include <hip/hip_runtime.h>
#include <hip/hip_bf16.h>
#include <math.h>

// Problem constants
#define Bsz 256
#define Hh 26
#define Ww 26
#define Ll 624
#define DDc 128
#define CHc 256
#define NLl 4
#define NPIX (Hh * Ww)            // 676
#define NROWS (Bsz * NPIX)        // 173056
#define GRID_ELEMS (NROWS * DDc)  // 22151168

typedef short short8v __attribute__((ext_vector_type(8)));   // 8 bf16 (4 VGPRs)
typedef float f32x4 __attribute__((ext_vector_type(4)));
typedef unsigned short ushort4v __attribute__((ext_vector_type(4)));

__device__ __forceinline__ unsigned short f2bf(float f) {
    union { float f; unsigned int u; } v; v.f = f;
    unsigned int u = v.u;
    return (unsigned short)((u + 0x7FFFu + ((u >> 16) & 1u)) >> 16);   // RNE
}

// Branchless gelu via Abramowitz-Stegun 7.1.26 erf (|err| < 1.5e-7)
__device__ __forceinline__ float fast_gelu(float x) {
    float z = x * 0.70710678118654752f;
    float a = fabsf(z);
    float t = 1.0f / fmaf(0.3275911f, a, 1.0f);
    float p = fmaf(1.061405429f, t, -1.453152027f);
    p = fmaf(p, t, 1.421413741f);
    p = fmaf(p, t, -0.284496736f);
    p = fmaf(p, t, 0.254829592f);
    float e = __expf(-a * a);
    float y = fmaf(-p * t, e, 1.0f);
    float er = copysignf(y, z);
    return 0.5f * x * (1.0f + er);
}

// ---------------------------------------------------------------------------
__global__ void build_inv_kernel(const int* __restrict__ coords, int* __restrict__ inv) {
    int i = threadIdx.x;
    if (i < NPIX) inv[i] = -1;
    __syncthreads();
    if (i < Ll) {
        int r = coords[2 * i + 0];
        int c = coords[2 * i + 1];
        inv[r * Ww + c] = i;
    }
}

// ---------------------------------------------------------------------------
__global__ __launch_bounds__(256) void scatter_kernel(const float* __restrict__ X,
                                                      const float* __restrict__ P,
                                                      const int* __restrict__ inv,
                                                      float* __restrict__ Y) {
    int idx = blockIdx.x * blockDim.x + threadIdx.x;
    int r = idx >> 5;
    int c4 = idx & 31;
    int b = r / NPIX;
    int pos = r - b * NPIX;
    int li = inv[pos];
    float4 v;
    if (li >= 0) v = *(const float4*)(X + ((size_t)(b * Ll + li) * DDc + c4 * 4));
    else         v = *(const float4*)(P + c4 * 4);
    *(float4*)(Y + ((size_t)r * DDc + c4 * 4)) = v;
}

// ---------------------------------------------------------------------------
__global__ __launch_bounds__(256) void wprep_kernel(const float* __restrict__ in,
                                                    unsigned short* __restrict__ out,
                                                    int R, int C) {
    __shared__ float t[32][33];
    int bz = blockIdx.z;
    const float* ip = in + (size_t)bz * R * C;
    unsigned short* op = out + (size_t)bz * R * C;
    int c0 = blockIdx.x * 32, r0 = blockIdx.y * 32;
    int tx = threadIdx.x & 31, ty = threadIdx.x >> 5;   // 32 x 8
#pragma unroll
    for (int i = 0; i < 32; i += 8)
        t[ty + i][tx] = ip[(size_t)(r0 + ty + i) * C + c0 + tx];
    __syncthreads();
#pragma unroll
    for (int i = 0; i < 32; i += 8)
        op[(size_t)(c0 + ty + i) * R + r0 + tx] = f2bf(t[tx][ty + i]);
}

// ---------------------------------------------------------------------------
__global__ __launch_bounds__(256) void ln_kernel(const float* __restrict__ Y,
                                                 const float* __restrict__ scale,
                                                 const float* __restrict__ bias,
                                                 unsigned short* __restrict__ Yn) {
    int wave = threadIdx.x >> 6;
    int lane = threadIdx.x & 63;
    int r = blockIdx.x * 4 + wave;
    const float* yr = Y + (size_t)r * DDc;
    float2 v = *(const float2*)(yr + lane * 2);
    float s = v.x + v.y;
#pragma unroll
    for (int off = 32; off >= 1; off >>= 1) s += __shfl_xor(s, off, 64);
    float mean = s * (1.0f / 128.0f);
    float dx = v.x - mean, dy = v.y - mean;
    float s2 = dx * dx + dy * dy;
#pragma unroll
    for (int off = 32; off >= 1; off >>= 1) s2 += __shfl_xor(s2, off, 64);
    float rstd = rsqrtf(s2 * (1.0f / 128.0f) + 1e-5f);
    float2 sc = *(const float2*)(scale + lane * 2);
    float2 bi = *(const float2*)(bias + lane * 2);
    ushort2 o;
    o.x = f2bf(dx * rstd * sc.x + bi.x);
    o.y = f2bf(dy * rstd * sc.y + bi.y);
    *(ushort2*)(Yn + (size_t)r * DDc + lane * 2) = o;
}

// ---------------------------------------------------------------------------
// Fused MFMA layer kernel. Block = (b, row-pair), 256 threads = 4 waves.
// LDS: A-slab [4 rows][28 cols][128ch bf16] (28672 B) ALIASED with
//      H [64 m][256 n bf16] (32768 B)  -- safe: barrier separates last A-read
//      from first H-write.  + 256 B zero pad region. Total 33024 B -> 4 blk/CU by LDS.
// Conv MFMAs are operand-SWAPPED: acc = mfma(Wfrag, Actfrag) so each lane holds
// col=m (al) and 4 consecutive n in regs -> packed b64 H-writes.
#define Z_OFF 32768
#define LDS_TOTAL 33024

__global__ __launch_bounds__(256, 3) void conv_mfma_kernel(
    const unsigned short* __restrict__ Yn,
    const unsigned short* __restrict__ w3bt,   // [9][256 n][128 k] bf16
    const float* __restrict__ b3l,
    const unsigned short* __restrict__ w1bt,   // [128 d][256 n] bf16
    const float* __restrict__ b1l,
    float* __restrict__ Y) {
    __shared__ __align__(16) char lds[LDS_TOTAL];

    int bx = blockIdx.x;
    int b = bx / 13;
    int h0 = (bx - b * 13) * 2;
    int tid = threadIdx.x;
    int lane = tid & 63, wv = tid >> 6;
    int al = lane & 15, ah = lane >> 4;

    // ---- stage A: rows h0-1..h0+2, cols -1..26, 128ch bf16, XOR-swizzled rows
    for (int i = tid; i < 4 * 28 * 16; i += 256) {     // 16B chunks
        int row4 = i / (28 * 16);
        int rem = i - row4 * (28 * 16);
        int col = rem >> 4;
        int c8 = (rem & 15) << 3;
        int hs = h0 - 1 + row4;
        int ws = col - 1;
        uint4 v = make_uint4(0u, 0u, 0u, 0u);
        if (hs >= 0 && hs < Hh && ws >= 0 && ws < Ww)
            v = *(const uint4*)(Yn + (((size_t)(b * Hh + hs) * Ww + ws) << 7) + c8);
        int r = row4 * 28 + col;
        unsigned int addr = (unsigned int)(r * 256 + c8 * 2);
        addr ^= (unsigned int)((r & 7) << 4);
        *(uint4*)(lds + addr) = v;
    }
    if (tid < 16) *(uint4*)(lds + Z_OFF + tid * 16) = make_uint4(0u, 0u, 0u, 0u);
    __syncthreads();

    // ---- per-lane M decomposition (m = mt*16 + al)
    int r00[4]; bool mpad[4];
#pragma unroll
    for (int mt = 0; mt < 4; ++mt) {
        int m = mt * 16 + al;
        bool pad = (m >= 52);
        int rh = (m >= 26) ? 1 : 0;
        int w = m - rh * 26;
        if (pad) { rh = 1; w = 0; }
        mpad[mt] = pad;
        r00[mt] = rh * 28 + w;
    }

    // ---- conv 3x3 via swapped MFMA, software-pipelined depth 1
    f32x4 acc[4][4];
#pragma unroll
    for (int mt = 0; mt < 4; ++mt)
#pragma unroll
        for (int nt = 0; nt < 4; ++nt) acc[mt][nt] = (f32x4)0.0f;

    int nw0 = wv * 64;
    const unsigned short* pB = w3bt + ((size_t)(nw0 + al) << 7) + ah * 8;
    const unsigned short* pBt = pB;

    unsigned int ah16 = (unsigned int)(ah * 16);
    unsigned int abase[4];
#pragma unroll
    for (int mt = 0; mt < 4; ++mt) {
        int row = r00[mt];                        // tap 0: dh=0,dw=0
        unsigned int sw = (unsigned int)((row & 7) << 4);
        abase[mt] = mpad[mt] ? (unsigned int)(Z_OFF) + ah16
                             : ((unsigned int)(row << 8) + (ah16 ^ sw));
    }

    short8v bc[4], afc[4];
#pragma unroll
    for (int nt = 0; nt < 4; ++nt) bc[nt] = *(const short8v*)(pBt + nt * 2048);
#pragma unroll
    for (int mt = 0; mt < 4; ++mt) afc[mt] = *(const short8v*)(lds + abase[mt]);

    int dh = 0, dw = 0;
#pragma unroll 1
    for (int tap = 0; tap < 9; ++tap) {
        // next tap's A row bases
        int dwn = dw + 1, dhn = dh;
        if (dwn == 3) { dwn = 0; dhn += 1; }
        unsigned int abasen[4];
#pragma unroll
        for (int mt = 0; mt < 4; ++mt) {
            int row = r00[mt] + dhn * 28 + dwn;
            if (row > 111) row = 111;             // tap==8 dummy prefetch clamp
            unsigned int sw = (unsigned int)((row & 7) << 4);
            abasen[mt] = mpad[mt] ? (unsigned int)(Z_OFF) + ah16
                                  : ((unsigned int)(row << 8) + (ah16 ^ sw));
        }
#pragma unroll
        for (int ks = 0; ks < 4; ++ks) {
            short8v bn[4], afn[4];
            const unsigned short* pn = (ks < 3) ? (pBt + (ks + 1) * 32) : (pBt + 32768);
#pragma unroll
            for (int nt = 0; nt < 4; ++nt) bn[nt] = *(const short8v*)(pn + nt * 2048);
#pragma unroll
            for (int mt = 0; mt < 4; ++mt) {
                unsigned int a = (ks < 3) ? (abase[mt] ^ (unsigned int)((ks + 1) << 6))
                                          : abasen[mt];
                afn[mt] = *(const short8v*)(lds + a);
            }
#pragma unroll
            for (int mt = 0; mt < 4; ++mt)
#pragma unroll
                for (int nt = 0; nt < 4; ++nt)
                    acc[mt][nt] = __builtin_amdgcn_mfma_f32_16x16x32_bf16(
                        bc[nt], afc[mt], acc[mt][nt], 0, 0, 0);
#pragma unroll
            for (int nt = 0; nt < 4; ++nt) bc[nt] = bn[nt];
#pragma unroll
            for (int mt = 0; mt < 4; ++mt) afc[mt] = afn[mt];
        }
#pragma unroll
        for (int mt = 0; mt < 4; ++mt) abase[mt] = abasen[mt];
        pBt += 32768;
        dw = dwn; dh = dhn;
    }
    __syncthreads();   // all A-reads done; H region may now overwrite A region

    // ---- bias + gelu -> H [64 m][256 n] bf16, packed b64 writes
    unsigned int hswz = ((unsigned int)(al & 7)) << 4;   // m&7 == al&7
#pragma unroll
    for (int nt = 0; nt < 4; ++nt) {
        int n0 = nw0 + nt * 16 + ah * 4;
        float4 bv = *(const float4*)(b3l + n0);
#pragma unroll
        for (int mt = 0; mt < 4; ++mt) {
            int m = mt * 16 + al;
            ushort4v o;
            o[0] = f2bf(fast_gelu(acc[mt][nt][0] + bv.x));
            o[1] = f2bf(fast_gelu(acc[mt][nt][1] + bv.y));
            o[2] = f2bf(fast_gelu(acc[mt][nt][2] + bv.z));
            o[3] = f2bf(fast_gelu(acc[mt][nt][3] + bv.w));
            unsigned int addr = ((unsigned int)(m * 512 + n0 * 2)) ^ hswz;
            *(ushort4v*)(lds + addr) = o;
        }
    }
    __syncthreads();

    // ---- 1x1 via MFMA: [64 x 256] @ [256 -> 128]
    f32x4 acc1[4][2];
#pragma unroll
    for (int mt = 0; mt < 4; ++mt) { acc1[mt][0] = (f32x4)0.0f; acc1[mt][1] = (f32x4)0.0f; }
    int nw1 = wv * 32;
    const unsigned short* pW1 = w1bt + ((size_t)(nw1 + al) << 8) + ah * 8;

#pragma unroll
    for (int ks = 0; ks < 8; ++ks) {
        short8v hf[4], wf[2];
#pragma unroll
        for (int mt = 0; mt < 4; ++mt) {
            unsigned int a = ((unsigned int)((mt * 16 + al) * 512 + ks * 64 + ah * 16)) ^ hswz;
            hf[mt] = *(const short8v*)(lds + a);
        }
        wf[0] = *(const short8v*)(pW1 + ks * 32);
        wf[1] = *(const short8v*)(pW1 + 4096 + ks * 32);
#pragma unroll
        for (int mt = 0; mt < 4; ++mt)
#pragma unroll
            for (int ntl = 0; ntl < 2; ++ntl)
                acc1[mt][ntl] = __builtin_amdgcn_mfma_f32_16x16x32_bf16(
                    hf[mt], wf[ntl], acc1[mt][ntl], 0, 0, 0);
    }

    // ---- bias + residual into Y (fp32)
#pragma unroll
    for (int ntl = 0; ntl < 2; ++ntl) {
        int n = nw1 + ntl * 16 + al;
        float bias = b1l[n];
#pragma unroll
        for (int mt = 0; mt < 4; ++mt) {
#pragma unroll
            for (int j = 0; j < 4; ++j) {
                int m = mt * 16 + ah * 4 + j;
                if (m < 52) {
                    int rh = (m >= 26) ? 1 : 0;
                    int w = m - rh * 26;
                    float* yp = Y + (((size_t)(b * Hh + h0 + rh) * Ww + w) << 7) + n;
                    *yp += acc1[mt][ntl][j] + bias;
                }
            }
        }
    }
}

// ---------------------------------------------------------------------------
__global__ __launch_bounds__(256) void gather_kernel(const float* __restrict__ Y,
                                                     const int* __restrict__ coords,
                                                     float* __restrict__ Z) {
    int idx = blockIdx.x * blockDim.x + threadIdx.x;
    int r = idx >> 5;
    int c4 = idx & 31;
    int b = r / Ll;
    int li = r - b * Ll;
    int row = coords[2 * li + 0];
    int col = coords[2 * li + 1];
    float4 v = *(const float4*)(Y + (((size_t)(b * NPIX + row * Ww + col)) * DDc + c4 * 4));
    *(float4*)(Z + ((size_t)r * DDc + c4 * 4)) = v;
}

// ---------------------------------------------------------------------------
extern "C" void kernel_launch(void* const* d_in, const int* in_sizes, int n_in,
                              void* d_out, int out_size, void* d_ws, size_t ws_size,
                              hipStream_t stream) {
    const float* X = (const float*)d_in[0];
    const int* coords = (const int*)d_in[1];
    const float* P = (const float*)d_in[2];
    const float* ln_scale = (const float*)d_in[3];
    const float* ln_bias = (const float*)d_in[4];
    const float* w3 = (const float*)d_in[5];
    const float* b3 = (const float*)d_in[6];
    const float* w1 = (const float*)d_in[7];
    const float* b1 = (const float*)d_in[8];

    float* Y = (float*)d_ws;
    unsigned short* Yn = (unsigned short*)(Y + GRID_ELEMS);
    unsigned short* w3bt = Yn + GRID_ELEMS;
    unsigned short* w1bt = w3bt + (size_t)NLl * 9 * CHc * DDc;
    int* inv = (int*)(w1bt + (size_t)NLl * DDc * CHc);

    build_inv_kernel<<<1, 1024, 0, stream>>>(coords, inv);

    wprep_kernel<<<dim3(CHc / 32, DDc / 32, NLl * 9), 256, 0, stream>>>(w3, w3bt, DDc, CHc);
    wprep_kernel<<<dim3(DDc / 32, CHc / 32, NLl), 256, 0, stream>>>(w1, w1bt, CHc, DDc);

    scatter_kernel<<<(NROWS * 32) / 256, 256, 0, stream>>>(X, P, inv, Y);

    for (int l = 0; l < NLl; ++l) {
        ln_kernel<<<NROWS / 4, 256, 0, stream>>>(Y, ln_scale + l * DDc, ln_bias + l * DDc, Yn);
        conv_mfma_kernel<<<Bsz * 13, 256, 0, stream>>>(
            Yn,
            w3bt + (size_t)l * 9 * CHc * DDc,
            b3 + (size_t)l * CHc,
            w1bt + (size_t)l * DDc * CHc,
            b1 + (size_t)l * DDc,
            Y);
    }

    gather_kernel<<<(Bsz * Ll * 32) / 256, 256, 0, stream>>>(Y, coords, (float*)d_out);
}